// Round 1
// baseline (508.349 us; speedup 1.0000x reference)
//
#include <hip/hip_runtime.h>
#include <math.h>

#define VOCAB 50000
#define DW 300
#define DH 50
#define G4 200   // 4*DH gate width
#define BATCH 1024
#define TMAX 200
#define OUTC 4
#define MT 40    // vocab rows per block in proj_kernel (50000/40 = 1250 exact)

// Kernel A: emb_proj[v][u] = sum_k emb[v][k]*w_ih[u][k] + b_ih[u] + b_hh[u]
__global__ __launch_bounds__(256) void proj_kernel(
    const float* __restrict__ emb, const float* __restrict__ w_ih,
    const float* __restrict__ b_ih, const float* __restrict__ b_hh,
    float* __restrict__ emb_proj)
{
    __shared__ __align__(16) float emb_s[MT * DW];
    const int tid = threadIdx.x;
    const int v0 = blockIdx.x * MT;

    // stage 40 emb rows (12000 floats) coalesced as float4
    {
        const float4* src = (const float4*)(emb + (size_t)v0 * DW);
        float4* dst = (float4*)emb_s;
        for (int i = tid; i < MT * DW / 4; i += 256) dst[i] = src[i];
    }
    __syncthreads();

    if (tid < G4) {
        const int u = tid;
        float acc[MT];
#pragma unroll
        for (int v = 0; v < MT; v++) acc[v] = 0.f;

        const float4* wrow = (const float4*)(w_ih + u * DW);
        for (int kk = 0; kk < DW / 4; kk++) {
            float4 w4 = wrow[kk];   // per-lane stream, L2-resident (240 KB total)
#pragma unroll
            for (int v = 0; v < MT; v++) {
                // same address across all lanes -> LDS broadcast (free)
                float4 e4 = *(const float4*)&emb_s[v * DW + kk * 4];
                acc[v] += w4.x * e4.x + w4.y * e4.y + w4.z * e4.z + w4.w * e4.w;
            }
        }
        float bias = b_ih[u] + b_hh[u];
#pragma unroll
        for (int v = 0; v < MT; v++) {
            // consecutive u across lanes -> coalesced 800B row stores
            emb_proj[(size_t)(v0 + v) * G4 + u] = acc[v] + bias;
        }
    }
}

// Kernel B: one block per batch element; loops exactly lengs[b] steps
// (mask semantics == frozen state after lengs[b], so early stop is exact).
__global__ __launch_bounds__(256) void lstm_kernel(
    const int* __restrict__ x, const int* __restrict__ lengs,
    const float* __restrict__ emb_proj, const float* __restrict__ w_hh,
    const float* __restrict__ w_out, const float* __restrict__ b_out,
    float* __restrict__ out)
{
    __shared__ __align__(16) float h_s[56];   // 50 + zero pad for float4 reads
    __shared__ float g_s[G4];
    __shared__ int   x_s[TMAX];
    __shared__ float logit_s[OUTC];

    const int tid = threadIdx.x;
    const int b   = blockIdx.x;
    const int len = lengs[b];                 // uniform per block, in [1,200]

    if (tid < TMAX) x_s[tid] = x[b * TMAX + tid];
    if (tid < 56)   h_s[tid] = 0.f;

    // each gate-thread keeps its w_hh row in registers (52 floats, padded)
    float r_w[52];
    if (tid < G4) {
#pragma unroll
        for (int k = 0; k < DH; k++) r_w[k] = w_hh[tid * DH + k];
        r_w[50] = 0.f; r_w[51] = 0.f;
    }
    __syncthreads();

    float c_reg = 0.f;
    // prefetch gate-input row for t=0 (indices known in advance)
    float gin_next = (tid < G4) ? emb_proj[(size_t)x_s[0] * G4 + tid] : 0.f;

    for (int t = 0; t < len; t++) {
        float gin_cur = gin_next;
        if (t + 1 < len && tid < G4)
            gin_next = emb_proj[(size_t)x_s[t + 1] * G4 + tid];  // hide L2/L3 latency

        if (tid < G4) {
            float acc = gin_cur;
#pragma unroll
            for (int k4 = 0; k4 < 13; k4++) {
                // all lanes read the same address -> broadcast
                float4 h4 = *(const float4*)&h_s[k4 * 4];
                acc += h4.x * r_w[k4 * 4 + 0] + h4.y * r_w[k4 * 4 + 1]
                     + h4.z * r_w[k4 * 4 + 2] + h4.w * r_w[k4 * 4 + 3];
            }
            g_s[tid] = acc;
        }
        __syncthreads();

        if (tid < DH) {
            float gi = g_s[tid], gf = g_s[tid + DH];
            float gg = g_s[tid + 2 * DH], go = g_s[tid + 3 * DH];
            float si = 1.f / (1.f + expf(-gi));
            float sf = 1.f / (1.f + expf(-gf));
            float so = 1.f / (1.f + expf(-go));
            float cn = sf * c_reg + si * tanhf(gg);
            c_reg = cn;
            h_s[tid] = so * tanhf(cn);
        }
        __syncthreads();
    }

    // logits = h @ w_out.T + b_out, then softmax over 4
    if (tid < OUTC) {
        float l = b_out[tid];
#pragma unroll
        for (int j = 0; j < DH; j++) l += h_s[j] * w_out[tid * DH + j];
        logit_s[tid] = l;
    }
    __syncthreads();
    if (tid < OUTC) {
        float m = fmaxf(fmaxf(logit_s[0], logit_s[1]),
                        fmaxf(logit_s[2], logit_s[3]));
        float s = 0.f;
#pragma unroll
        for (int j = 0; j < OUTC; j++) s += expf(logit_s[j] - m);
        out[b * OUTC + tid] = expf(logit_s[tid] - m) / s;
    }
}

extern "C" void kernel_launch(void* const* d_in, const int* in_sizes, int n_in,
                              void* d_out, int out_size, void* d_ws, size_t ws_size,
                              hipStream_t stream) {
    const int*   x     = (const int*)d_in[0];
    const int*   lengs = (const int*)d_in[1];
    const float* emb   = (const float*)d_in[2];
    const float* w_ih  = (const float*)d_in[3];
    const float* w_hh  = (const float*)d_in[4];
    const float* b_ih  = (const float*)d_in[5];
    const float* b_hh  = (const float*)d_in[6];
    const float* w_out = (const float*)d_in[7];
    const float* b_out = (const float*)d_in[8];
    float* out = (float*)d_out;

    float* emb_proj = (float*)d_ws;   // 50000*200*4 = 40 MB scratch

    hipLaunchKernelGGL(proj_kernel, dim3(VOCAB / MT), dim3(256), 0, stream,
                       emb, w_ih, b_ih, b_hh, emb_proj);
    hipLaunchKernelGGL(lstm_kernel, dim3(BATCH), dim3(256), 0, stream,
                       x, lengs, emb_proj, w_hh, w_out, b_out, out);
}

// Round 2
// 353.902 us; speedup vs baseline: 1.4364x; 1.4364x over previous
//
#include <hip/hip_runtime.h>
#include <math.h>

#define VOCAB 50000
#define DW 300
#define DH 50
#define G4 200
#define BATCH 1024
#define TMAX 200
#define OUTC 4

// ---------------------------------------------------------------------------
// Kernel 0: transpose w_ih [200][300] -> w_T [300][200] (so proj reads are
// coalesced across the N dimension on the VMEM pipe).
__global__ __launch_bounds__(256) void transpose_wih(
    const float* __restrict__ w_ih, float* __restrict__ w_T)
{
    int i = blockIdx.x * 256 + threadIdx.x;
    if (i < G4 * DW) {
        int u = i / DW, k = i % DW;
        w_T[k * G4 + u] = w_ih[i];
    }
}

// ---------------------------------------------------------------------------
// Kernel A: emb_proj[v][u2] = sum_k emb[v][k]*w_ih[u][k] + b_ih[u] + b_hh[u]
// with gate-permuted columns u2 = (u%50)*4 + u/50 so the LSTM gather is one
// float4 per lane. Register tile 10M x 8N per thread; emb broadcast from LDS
// (10 ds_read_b128 per 320 FMA -> LDS pipe ~29us < VALU ~39us); w_T streamed
// from L2. Tile 100M x 200N, 500 blocks (~2/CU, balanced).
__global__ __launch_bounds__(256, 2) void proj_kernel(
    const float* __restrict__ emb, const float* __restrict__ w_T,
    const float* __restrict__ b_ih, const float* __restrict__ b_hh,
    float* __restrict__ emb_proj)
{
    __shared__ __align__(16) float e_s[100 * 108];  // rows padded to 108 dwords
    const int tid = threadIdx.x;
    const int v0 = blockIdx.x * 100;
    const int m_idx = tid / 25;   // 0..9 (valid for tid<250)
    const int n_idx = tid % 25;   // 0..24

    float acc[10][8];
#pragma unroll
    for (int m = 0; m < 10; m++)
#pragma unroll
        for (int c = 0; c < 8; c++) acc[m][c] = 0.f;

    for (int kc = 0; kc < DW; kc += 100) {
        __syncthreads();   // protect previous chunk reads
        // stage 100 rows x 100 cols (16B-aligned: 1200B row stride, 400B kc)
        for (int i = tid; i < 2500; i += 256) {
            int r = i / 25, c = i % 25;
            float4 v = *(const float4*)&emb[(size_t)(v0 + r) * DW + kc + c * 4];
            *(float4*)&e_s[r * 108 + c * 4] = v;
        }
        __syncthreads();

        if (tid < 250) {
#pragma unroll 2
            for (int kk = 0; kk < 25; kk++) {
                float4 e4[10];
#pragma unroll
                for (int m = 0; m < 10; m++)
                    e4[m] = *(const float4*)&e_s[(m_idx * 10 + m) * 108 + kk * 4];
                const float* wbase = w_T + (size_t)(kc + kk * 4) * G4 + n_idx * 8;
#pragma unroll
                for (int j = 0; j < 4; j++) {
                    float4 wa = *(const float4*)(wbase + j * G4);
                    float4 wb = *(const float4*)(wbase + j * G4 + 4);
#pragma unroll
                    for (int m = 0; m < 10; m++) {
                        float ev = (j == 0) ? e4[m].x : (j == 1) ? e4[m].y
                                 : (j == 2) ? e4[m].z : e4[m].w;
                        acc[m][0] = fmaf(ev, wa.x, acc[m][0]);
                        acc[m][1] = fmaf(ev, wa.y, acc[m][1]);
                        acc[m][2] = fmaf(ev, wa.z, acc[m][2]);
                        acc[m][3] = fmaf(ev, wa.w, acc[m][3]);
                        acc[m][4] = fmaf(ev, wb.x, acc[m][4]);
                        acc[m][5] = fmaf(ev, wb.y, acc[m][5]);
                        acc[m][6] = fmaf(ev, wb.z, acc[m][6]);
                        acc[m][7] = fmaf(ev, wb.w, acc[m][7]);
                    }
                }
            }
        }
    }

    if (tid < 250) {
#pragma unroll
        for (int c = 0; c < 8; c++) {
            int u = n_idx * 8 + c;
            float bias = b_ih[u] + b_hh[u];
            int u2 = (u % DH) * 4 + (u / DH);   // gate-permuted column
#pragma unroll
            for (int m = 0; m < 10; m++)
                emb_proj[(size_t)(v0 + m_idx * 10 + m) * G4 + u2] = acc[m][c] + bias;
        }
    }
}

// ---------------------------------------------------------------------------
// Kernel B: one 64-lane wave per batch element. Lane l owns hidden unit l and
// all 4 of its w_hh gate rows in registers (~208 VGPR; launch_bounds(64,1)
// allows up to 512 so no spill). No barriers: single-wave lockstep keeps LDS
// ops in program order. Gather prefetched 2 steps ahead (one float4/lane from
// the gate-permuted emb_proj). Early exit at lengs[b] is exact (mask==freeze).
__device__ __forceinline__ float tanh_f(float x) {
    float e2 = __expf(fminf(2.f * x, 60.f));
    return (e2 - 1.f) / (e2 + 1.f);
}

__global__ __launch_bounds__(64, 1) void lstm_kernel(
    const int* __restrict__ x, const int* __restrict__ lengs,
    const float* __restrict__ emb_proj, const float* __restrict__ w_hh,
    const float* __restrict__ w_out, const float* __restrict__ b_out,
    float* __restrict__ out)
{
    __shared__ __align__(16) float h_s[52];
    __shared__ int x_s[TMAX];
    __shared__ float red[OUTC];

    const int l  = threadIdx.x;
    const int b  = blockIdx.x;
    const int ll = (l < DH) ? l : DH - 1;       // lanes 50-63: harmless dup
    const int len = lengs[b];

    for (int i = l; i < TMAX; i += 64) x_s[i] = x[b * TMAX + i];
    if (l < 52) h_s[l] = 0.f;

    // w_hh rows for gates i,f,g,o of unit ll -> registers (float2: 8B aligned)
    float4 rwi[13], rwf[13], rwg[13], rwo[13];
    {
        const float* wr;
#define LOADROW(dst, gate)                                                    \
        wr = w_hh + (size_t)((gate) * DH + ll) * DH;                          \
        _Pragma("unroll")                                                     \
        for (int k4 = 0; k4 < 12; k4++) {                                     \
            float2 a = *(const float2*)(wr + 4 * k4);                         \
            float2 bb = *(const float2*)(wr + 4 * k4 + 2);                    \
            dst[k4] = make_float4(a.x, a.y, bb.x, bb.y);                      \
        }                                                                     \
        { float2 a = *(const float2*)(wr + 48);                               \
          dst[12] = make_float4(a.x, a.y, 0.f, 0.f); }
        LOADROW(rwi, 0) LOADROW(rwf, 1) LOADROW(rwg, 2) LOADROW(rwo, 3)
#undef LOADROW
    }

    float c_reg = 0.f;
    const float* ep = emb_proj;
    float4 p0 = *(const float4*)(ep + (size_t)x_s[0] * G4 + 4 * ll);
    float4 p1 = *(const float4*)(ep + (size_t)x_s[1 < TMAX ? 1 : 0] * G4 + 4 * ll);

    for (int t = 0; t < len; t++) {
        float4 cur = p0;
        p0 = p1;
        int nt = (t + 2 < TMAX) ? t + 2 : TMAX - 1;
        p1 = *(const float4*)(ep + (size_t)x_s[nt] * G4 + 4 * ll);

        float gi = cur.x, gf = cur.y, gc = cur.z, go = cur.w;
#pragma unroll
        for (int k4 = 0; k4 < 13; k4++) {
            float4 h4 = *(const float4*)&h_s[4 * k4];   // broadcast read
            gi = fmaf(h4.x, rwi[k4].x, fmaf(h4.y, rwi[k4].y,
                 fmaf(h4.z, rwi[k4].z, fmaf(h4.w, rwi[k4].w, gi))));
            gf = fmaf(h4.x, rwf[k4].x, fmaf(h4.y, rwf[k4].y,
                 fmaf(h4.z, rwf[k4].z, fmaf(h4.w, rwf[k4].w, gf))));
            gc = fmaf(h4.x, rwg[k4].x, fmaf(h4.y, rwg[k4].y,
                 fmaf(h4.z, rwg[k4].z, fmaf(h4.w, rwg[k4].w, gc))));
            go = fmaf(h4.x, rwo[k4].x, fmaf(h4.y, rwo[k4].y,
                 fmaf(h4.z, rwo[k4].z, fmaf(h4.w, rwo[k4].w, go))));
        }
        float si = 1.f / (1.f + __expf(-gi));
        float sf = 1.f / (1.f + __expf(-gf));
        float so = 1.f / (1.f + __expf(-go));
        float cn = fmaf(sf, c_reg, si * tanh_f(gc));
        c_reg = cn;
        float hn = so * tanh_f(cn);
        if (l < DH) h_s[l] = hn;   // same wave: program order, no barrier
    }

    // logits + softmax (lanes 0-3)
    if (l < OUTC) {
        float lg = b_out[l];
        const float* wo = w_out + l * DH;
#pragma unroll
        for (int k = 0; k < DH; k++) lg = fmaf(h_s[k], wo[k], lg);
        red[l] = lg;
    }
    if (l < OUTC) {
        float m = fmaxf(fmaxf(red[0], red[1]), fmaxf(red[2], red[3]));
        float s = 0.f;
#pragma unroll
        for (int j = 0; j < OUTC; j++) s += __expf(red[j] - m);
        out[b * OUTC + l] = __expf(red[l] - m) / s;
    }
}

// ---------------------------------------------------------------------------
extern "C" void kernel_launch(void* const* d_in, const int* in_sizes, int n_in,
                              void* d_out, int out_size, void* d_ws, size_t ws_size,
                              hipStream_t stream) {
    const int*   x     = (const int*)d_in[0];
    const int*   lengs = (const int*)d_in[1];
    const float* emb   = (const float*)d_in[2];
    const float* w_ih  = (const float*)d_in[3];
    const float* w_hh  = (const float*)d_in[4];
    const float* b_ih  = (const float*)d_in[5];
    const float* b_hh  = (const float*)d_in[6];
    const float* w_out = (const float*)d_in[7];
    const float* b_out = (const float*)d_in[8];
    float* out = (float*)d_out;

    float* emb_proj = (float*)d_ws;                       // 40 MB
    float* w_T      = emb_proj + (size_t)VOCAB * G4;      // +240 KB

    hipLaunchKernelGGL(transpose_wih, dim3((G4 * DW + 255) / 256), dim3(256),
                       0, stream, w_ih, w_T);
    hipLaunchKernelGGL(proj_kernel, dim3(VOCAB / 100), dim3(256), 0, stream,
                       emb, w_T, b_ih, b_hh, emb_proj);
    hipLaunchKernelGGL(lstm_kernel, dim3(BATCH), dim3(64), 0, stream,
                       x, lengs, emb_proj, w_hh, w_out, b_out, out);
}